// Round 2
// baseline (167.191 us; speedup 1.0000x reference)
//
#include <hip/hip_runtime.h>
#include <stdint.h>
#include <stddef.h>

typedef __bf16 bf16_t;
typedef __bf16 bf16x8 __attribute__((ext_vector_type(8)));
typedef float  f32x4  __attribute__((ext_vector_type(4)));

#define NIMG 16
#define CIN  128
#define COUT 128
#define HH   56
#define WW   56
#define PR   58      // padded rows (1 + 56 + 1)
#define PCOL 66      // padded cols (1 + 56 + 1 + 8 slack for 64-wide sp tile)
#define CI_STRIDE 40 // LDS ci stride in bf16 (32 used + 8 pad; 80B keeps 16B alignment)

// P layout: uint4 units (8 bf16 along ci), index = ((n*PR + r)*16 + cig)*PCOL + c
//   -> itrans writes contiguous, conv staging reads contiguous.

// ---------- prologue 1: W[co][ci][3][3] fp32 -> Wt[khkw][co][ci] bf16 ----------
// thread per (co,ci): 9 contiguous reads (L1-merged), 9 coalesced 2B writes.
__global__ void wtrans_kernel(const float* __restrict__ w, bf16_t* __restrict__ wt) {
    int idx = blockIdx.x * 256 + threadIdx.x;    // 16384 threads
    int co = idx >> 7, ci = idx & 127;
    const float* src = w + (size_t)idx * 9;
    float v[9];
#pragma unroll
    for (int k = 0; k < 9; ++k) v[k] = src[k];
#pragma unroll
    for (int k = 0; k < 9; ++k)
        wt[(size_t)k * (COUT * CIN) + co * CIN + ci] = (bf16_t)v[k];
}

// ---------- prologue 2: gather-transpose, one uint4 (8 bf16 along ci) per thread ----------
__global__ void itrans_kernel(const float* __restrict__ in, uint4* __restrict__ P) {
    int idx = blockIdx.x * 256 + threadIdx.x;    // 3828*256 = 979968 exactly
    int c   = idx % PCOL;                        // fastest -> reads stride-1 in w
    int t1  = idx / PCOL;
    int cig = t1 & 15;
    int t2  = t1 >> 4;
    int r   = t2 % PR;
    int n   = t2 / PR;

    uint32_t u[8];
    if (r >= 1 && r <= HH && c >= 1 && c <= WW) {
        const float* src = in + (((size_t)n * CIN + cig * 8) * HH + (r - 1)) * WW + (c - 1);
        float v[8];
#pragma unroll
        for (int k = 0; k < 8; ++k) v[k] = src[(size_t)k * (HH * WW)];  // 8 independent loads
#pragma unroll
        for (int k = 0; k < 8; ++k) { bf16_t b = (bf16_t)v[k]; u[k] = *(const uint16_t*)&b; }
    } else {
#pragma unroll
        for (int k = 0; k < 8; ++k) u[k] = 0;
    }
    uint4 o;
    o.x = u[0] | (u[1] << 16); o.y = u[2] | (u[3] << 16);
    o.z = u[4] | (u[5] << 16); o.w = u[6] | (u[7] << 16);
    P[idx] = o;   // consecutive threads -> contiguous 16B
}

// ---------- main: implicit GEMM. block = (n, 1 output row) x 128 co, grid 896 ----------
// wave (ws,wc): ws = sp half (32 w), wc = co half (64 co); wave tile 32sp x 64co.
__global__ __launch_bounds__(256, 4)
void conv_mfma_kernel(const uint4* __restrict__ P, const bf16_t* __restrict__ Wt,
                      const float* __restrict__ bias, float* __restrict__ out) {
    __shared__ bf16_t lds[2][3 * PCOL * CI_STRIDE];   // 2 x 15840 B

    const int bx = blockIdx.x;
    const int n  = bx / HH;
    const int h  = bx % HH;                            // output row; padded rows h..h+2

    const int tid  = threadIdx.x;
    const int lane = tid & 63;
    const int wave = tid >> 6;
    const int ws  = wave & 1;
    const int wc  = wave >> 1;
    const int l15 = lane & 15;
    const int l4  = lane >> 4;

    // uint4 base for (n, r=h+rr, cig, c): rr*16*PCOL + (chunk*4+cg)*PCOL + c
    const uint4* Pb = P + (size_t)(n * PR + h) * (16 * PCOL);

    f32x4 acc[4][2];
#pragma unroll
    for (int a = 0; a < 4; ++a)
#pragma unroll
        for (int b2 = 0; b2 < 2; ++b2) acc[a][b2] = (f32x4){0.f, 0.f, 0.f, 0.f};

    uint4 stg[4];   // staging: 3 rows x 4 cig x 66 c = 792 uint4 per chunk

    // ---- stage chunk 0 (ci 0..31)
#pragma unroll
    for (int it = 0; it < 4; ++it) {
        int G = it * 256 + tid;
        if (G < 792) {
            int rr = G / 264, rem = G % 264;           // rem = cg*66 + c
            stg[it] = Pb[rr * (16 * PCOL) + rem];      // chunk 0 offset = 0
        }
    }
#pragma unroll
    for (int it = 0; it < 4; ++it) {
        int G = it * 256 + tid;
        if (G < 792) {
            int rr = G / 264, rem = G % 264, cg = rem / 66, c = rem - cg * 66;
            *(uint4*)&lds[0][(rr * PCOL + c) * CI_STRIDE + cg * 8] = stg[it];
        }
    }
    __syncthreads();

    const bf16_t* wpbase = Wt + (size_t)(wc * 64 + l15) * CIN + l4 * 8;

    for (int chunk = 0; chunk < 4; ++chunk) {
        // prefetch next ci-chunk into regs (flies during compute)
        if (chunk < 3) {
#pragma unroll
            for (int it = 0; it < 4; ++it) {
                int G = it * 256 + tid;
                if (G < 792) {
                    int rr = G / 264, rem = G % 264;
                    stg[it] = Pb[rr * (16 * PCOL) + (chunk + 1) * 264 + rem];
                }
            }
        }

        const bf16_t* lb = lds[chunk & 1];
        const bf16_t* wp = wpbase + chunk * 32;
#pragma unroll
        for (int khkw = 0; khkw < 9; ++khkw) {
            const int kh = khkw / 3, kw = khkw % 3;
            bf16x8 af[4];
#pragma unroll
            for (int tc = 0; tc < 4; ++tc)
                af[tc] = *(const bf16x8*)(wp + (size_t)khkw * (COUT * CIN) + tc * 16 * CIN);
#pragma unroll
            for (int ts = 0; ts < 2; ++ts) {
                int c = ws * 32 + ts * 16 + l15 + kw;       // <= 65 < PCOL
                bf16x8 bfm = *(const bf16x8*)(lb + (kh * PCOL + c) * CI_STRIDE + l4 * 8);
#pragma unroll
                for (int tc = 0; tc < 4; ++tc)
                    acc[tc][ts] = __builtin_amdgcn_mfma_f32_16x16x32_bf16(
                        af[tc], bfm, acc[tc][ts], 0, 0, 0);
            }
        }

        if (chunk < 3) {
#pragma unroll
            for (int it = 0; it < 4; ++it) {
                int G = it * 256 + tid;
                if (G < 792) {
                    int rr = G / 264, rem = G % 264, cg = rem / 66, c = rem - cg * 66;
                    *(uint4*)&lds[(chunk + 1) & 1][(rr * PCOL + c) * CI_STRIDE + cg * 8] = stg[it];
                }
            }
        }
        __syncthreads();
    }

    // ---- epilogue: D col = lane&15 -> w, row = l4*4+i -> co
    const int co0 = wc * 64;
    float* obase = out + ((size_t)n * COUT) * (HH * WW) + (size_t)h * WW;
#pragma unroll
    for (int tc = 0; tc < 4; ++tc) {
#pragma unroll
        for (int ts = 0; ts < 2; ++ts) {
            int w0 = ws * 32 + ts * 16 + l15;
            if (w0 < WW) {
#pragma unroll
                for (int i = 0; i < 4; ++i) {
                    int co = co0 + tc * 16 + l4 * 4 + i;
                    obase[(size_t)co * (HH * WW) + w0] = acc[tc][ts][i] + bias[co];
                }
            }
        }
    }
}

extern "C" void kernel_launch(void* const* d_in, const int* in_sizes, int n_in,
                              void* d_out, int out_size, void* d_ws, size_t ws_size,
                              hipStream_t stream) {
    const float* in   = (const float*)d_in[0];
    const float* wgt  = (const float*)d_in[1];
    const float* bias = (const float*)d_in[2];
    float* out = (float*)d_out;

    uint4* P = (uint4*)d_ws;
    const size_t P_bytes = (size_t)NIMG * PR * 16 * PCOL * 16;  // 15,679,488 B
    bf16_t* Wt = (bf16_t*)((char*)d_ws + P_bytes);              // +294,912 B

    wtrans_kernel<<<64, 256, 0, stream>>>(wgt, Wt);
    itrans_kernel<<<3828, 256, 0, stream>>>(in, P);
    conv_mfma_kernel<<<NIMG * HH, 256, 0, stream>>>(P, Wt, bias, out);
}

// Round 3
// 120.890 us; speedup vs baseline: 1.3830x; 1.3830x over previous
//
#include <hip/hip_runtime.h>
#include <stdint.h>
#include <stddef.h>

typedef __bf16 bf16_t;
typedef __bf16 bf16x8 __attribute__((ext_vector_type(8)));
typedef float  f32x4  __attribute__((ext_vector_type(4)));

#define NIMG 16
#define CIN  128
#define COUT 128
#define HH   56
#define WW   56
#define HW   (HH * WW)       // 3136
#define CDIM 58              // staged c extent: c = w+1, w = -1..56
#define ROWPAIRS 28

// ---------- prologue: W[co][ci][3][3] fp32 -> Wt[khkw][co][ci] bf16 ----------
__global__ void wtrans_kernel(const float* __restrict__ w, bf16_t* __restrict__ wt) {
    int idx = blockIdx.x * 256 + threadIdx.x;    // 16384 threads
    int co = idx >> 7, ci = idx & 127;
    const float* src = w + (size_t)idx * 9;
    float v[9];
#pragma unroll
    for (int k = 0; k < 9; ++k) v[k] = src[k];
#pragma unroll
    for (int k = 0; k < 9; ++k)
        wt[(size_t)k * (COUT * CIN) + co * CIN + ci] = (bf16_t)v[k];
}

// ---------- fused conv: block = (n, 2 output rows) x 128 co; 4 waves 64sp x 64co ----------
// K-loop: p = khkw*4 + ci_chunk (36 phases). Input resident in LDS (staged once);
// weights per-wave register-double-buffered from L2. No barriers in the K-loop.
__global__ __launch_bounds__(256, 2)
void conv_fused_kernel(const float* __restrict__ in, const bf16_t* __restrict__ Wt,
                       const float* __restrict__ bias, float* __restrict__ out) {
    __shared__ bf16_t inp[4 * CDIM * CIN];       // 59392 B -> 2 blocks/CU

    const int bx = blockIdx.x;
    const int n  = bx / ROWPAIRS;
    const int h0 = (bx % ROWPAIRS) * 2;          // output rows h0, h0+1; input rows h0-1..h0+2

    const int tid  = threadIdx.x;
    const int lane = tid & 63;
    const int wave = tid >> 6;
    const int ws  = wave & 1;                    // output row within pair
    const int wc  = wave >> 1;                   // co half (64)
    const int l15 = lane & 15;
    const int l4  = lane >> 4;

    // ---- stage input once: unit G = cig*232 + rr*58 + c  (c fastest -> contiguous walk)
#pragma unroll
    for (int it = 0; it < 15; ++it) {
        int G = it * 256 + tid;
        if (G < 3712) {
            int cig = G / 232, rem = G - cig * 232;
            int rr  = rem / 58, c  = rem - rr * 58;
            int r_in = h0 - 1 + rr, w = c - 1;
            uint32_t u[8];
            if (r_in >= 0 && r_in < HH && w >= 0 && w < WW) {
                const float* src = in + (((size_t)n * CIN + cig * 8) * HH + r_in) * WW + w;
                float v[8];
#pragma unroll
                for (int j = 0; j < 8; ++j) v[j] = src[(size_t)j * HW];   // 8 independent strided loads
#pragma unroll
                for (int j = 0; j < 8; ++j) { bf16_t b = (bf16_t)v[j]; u[j] = *(const uint16_t*)&b; }
            } else {
#pragma unroll
                for (int j = 0; j < 8; ++j) u[j] = 0;
            }
            uint4 o;
            o.x = u[0] | (u[1] << 16); o.y = u[2] | (u[3] << 16);
            o.z = u[4] | (u[5] << 16); o.w = u[6] | (u[7] << 16);
            *(uint4*)&inp[(rr * CDIM + c) * CIN + cig * 8] = o;
        }
    }
    __syncthreads();                             // the only barrier

    f32x4 acc[4][4];                             // [co tile][sp tile]
#pragma unroll
    for (int a = 0; a < 4; ++a)
#pragma unroll
        for (int b2 = 0; b2 < 4; ++b2) acc[a][b2] = (f32x4){0.f, 0.f, 0.f, 0.f};

    // per-wave weight fragment base: co = wc*64 + tc*16 + l15, ci octet l4
    const bf16_t* wpbase = Wt + (size_t)(wc * 64 + l15) * CIN + l4 * 8;

    bf16x8 afc[4], afn[4];
#pragma unroll
    for (int tc = 0; tc < 4; ++tc)
        afc[tc] = *(const bf16x8*)(wpbase + tc * 16 * CIN);       // phase 0: khkw=0, chunk=0

#pragma unroll 4
    for (int p = 0; p < 36; ++p) {
        const int khkw = p >> 2, chunk = p & 3;
        if (p < 35) {                            // prefetch next phase's weights (L2)
            const int pn = p + 1;
            const bf16_t* wp = wpbase + (size_t)(pn >> 2) * (COUT * CIN) + (pn & 3) * 32;
#pragma unroll
            for (int tc = 0; tc < 4; ++tc)
                afn[tc] = *(const bf16x8*)(wp + tc * 16 * CIN);
        }
        const int kh = khkw / 3, kw = khkw - kh * 3;
        const int r  = ws + kh;
        const bf16_t* lb = inp + (size_t)(r * CDIM) * CIN + chunk * 32 + l4 * 8;
#pragma unroll
        for (int ts = 0; ts < 4; ++ts) {
            int cb = ts * 16 + l15 + kw;
            if (cb > 57) cb = 57;                // only lanes whose outputs are discarded
            bf16x8 bfm = *(const bf16x8*)(lb + cb * CIN);
#pragma unroll
            for (int tc = 0; tc < 4; ++tc)
                acc[tc][ts] = __builtin_amdgcn_mfma_f32_16x16x32_bf16(
                    afc[tc], bfm, acc[tc][ts], 0, 0, 0);
        }
#pragma unroll
        for (int tc = 0; tc < 4; ++tc) afc[tc] = afn[tc];
    }

    // ---- epilogue: D col = lane&15 -> w, row = l4*4+i -> co  (R1-verified mapping)
    const int h   = h0 + ws;
    const int co0 = wc * 64;
    float* obase = out + ((size_t)n * COUT) * HW + (size_t)h * WW;
#pragma unroll
    for (int tc = 0; tc < 4; ++tc) {
#pragma unroll
        for (int ts = 0; ts < 4; ++ts) {
            int w0 = ts * 16 + l15;
            if (w0 < WW) {
#pragma unroll
                for (int i = 0; i < 4; ++i) {
                    int co = co0 + tc * 16 + l4 * 4 + i;
                    obase[(size_t)co * HW + w0] = acc[tc][ts][i] + bias[co];
                }
            }
        }
    }
}

extern "C" void kernel_launch(void* const* d_in, const int* in_sizes, int n_in,
                              void* d_out, int out_size, void* d_ws, size_t ws_size,
                              hipStream_t stream) {
    const float* in   = (const float*)d_in[0];
    const float* wgt  = (const float*)d_in[1];
    const float* bias = (const float*)d_in[2];
    float* out = (float*)d_out;

    bf16_t* Wt = (bf16_t*)d_ws;                  // 294,912 B

    wtrans_kernel<<<64, 256, 0, stream>>>(wgt, Wt);
    conv_fused_kernel<<<NIMG * ROWPAIRS, 256, 0, stream>>>(in, Wt, bias, out);
}

// Round 4
// 120.726 us; speedup vs baseline: 1.3849x; 1.0014x over previous
//
#include <hip/hip_runtime.h>
#include <stdint.h>
#include <stddef.h>

typedef __bf16 bf16_t;
typedef __bf16 bf16x8 __attribute__((ext_vector_type(8)));
typedef float  f32x4  __attribute__((ext_vector_type(4)));

#define NIMG 16
#define CIN  128
#define COUT 128
#define HH   56
#define WW   56
#define HW   (HH * WW)       // 3136
#define CDIM 58              // staged c extent: c = w+1, w = -1..56
#define LSTR 136             // LDS c-stride in bf16: 272B = 68 dwords -> bank stride 4 (2-way, free)
#define ROWPAIRS 28

// ---------- prologue: W[co][ci][3][3] fp32 -> Wt[khkw][co][ci] bf16 ----------
__global__ void wtrans_kernel(const float* __restrict__ w, bf16_t* __restrict__ wt) {
    int idx = blockIdx.x * 256 + threadIdx.x;    // 16384 threads
    int co = idx >> 7, ci = idx & 127;
    const float* src = w + (size_t)idx * 9;
    float v[9];
#pragma unroll
    for (int k = 0; k < 9; ++k) v[k] = src[k];
#pragma unroll
    for (int k = 0; k < 9; ++k)
        wt[(size_t)k * (COUT * CIN) + co * CIN + ci] = (bf16_t)v[k];
}

// ---------- fused conv: block = (n, 2 output rows) x 128 co; 4 waves 64sp x 64co ----------
// Input resident in LDS (staged once, padded stride); weights register-double-buffered
// from L2 with prefetch distance 2. No barriers in the 36-phase K-loop.
__global__ __launch_bounds__(256, 2)
void conv_fused_kernel(const float* __restrict__ in, const bf16_t* __restrict__ Wt,
                       const float* __restrict__ bias, float* __restrict__ out) {
    __shared__ bf16_t inp[4 * CDIM * LSTR];      // 63,104 B -> 2 blocks/CU

    const int bx = blockIdx.x;
    const int n  = bx / ROWPAIRS;
    const int h0 = (bx % ROWPAIRS) * 2;          // output rows h0, h0+1; input rows h0-1..h0+2

    const int tid  = threadIdx.x;
    const int lane = tid & 63;
    const int wave = tid >> 6;
    const int ws  = wave & 1;                    // output row within pair
    const int wc  = wave >> 1;                   // co half (64)
    const int l15 = lane & 15;
    const int l4  = lane >> 4;

    // ---- stage input once: unit G = cig*232 + rr*58 + c  (c fastest -> contiguous walk)
#pragma unroll
    for (int it = 0; it < 15; ++it) {
        int G = it * 256 + tid;
        if (G < 3712) {
            int cig = G / 232, rem = G - cig * 232;
            int rr  = rem / 58, c  = rem - rr * 58;
            int r_in = h0 - 1 + rr, w = c - 1;
            uint32_t u[8];
            if (r_in >= 0 && r_in < HH && w >= 0 && w < WW) {
                const float* src = in + (((size_t)n * CIN + cig * 8) * HH + r_in) * WW + w;
                float v[8];
#pragma unroll
                for (int j = 0; j < 8; ++j) v[j] = src[(size_t)j * HW];   // 8 independent strided loads
#pragma unroll
                for (int j = 0; j < 8; ++j) { bf16_t b = (bf16_t)v[j]; u[j] = *(const uint16_t*)&b; }
            } else {
#pragma unroll
                for (int j = 0; j < 8; ++j) u[j] = 0;
            }
            uint4 o;
            o.x = u[0] | (u[1] << 16); o.y = u[2] | (u[3] << 16);
            o.z = u[4] | (u[5] << 16); o.w = u[6] | (u[7] << 16);
            *(uint4*)&inp[(rr * CDIM + c) * LSTR + cig * 8] = o;
        }
    }
    __syncthreads();                             // the only barrier

    f32x4 acc[4][4];                             // [co tile][sp tile]
#pragma unroll
    for (int a = 0; a < 4; ++a)
#pragma unroll
        for (int b2 = 0; b2 < 4; ++b2) acc[a][b2] = (f32x4){0.f, 0.f, 0.f, 0.f};

    // per-wave weight fragment base: co = wc*64 + tc*16 + l15, ci octet l4
    const bf16_t* wpbase = Wt + (size_t)(wc * 64 + l15) * CIN + l4 * 8;

    // phase p = khkw*4 + chunk; weight frag addr(p) = wpbase + (p>>2)*COUT*CIN + (p&3)*32
    bf16x8 afa[4], afb[4];                       // rotating buffers, prefetch distance 2
#pragma unroll
    for (int tc = 0; tc < 4; ++tc)
        afa[tc] = *(const bf16x8*)(wpbase + tc * 16 * CIN);                      // p=0
#pragma unroll
    for (int tc = 0; tc < 4; ++tc)
        afb[tc] = *(const bf16x8*)(wpbase + 32 + tc * 16 * CIN);                 // p=1

#pragma unroll 4
    for (int p = 0; p < 36; ++p) {
        const int khkw = p >> 2, chunk = p & 3;
        const int kh = khkw / 3, kw = khkw - kh * 3;
        const int r  = ws + kh;
        const bf16_t* lb = inp + (size_t)(r * CDIM) * LSTR + chunk * 32 + l4 * 8;

        bf16x8* cur = (p & 1) ? afb : afa;
#pragma unroll
        for (int ts = 0; ts < 4; ++ts) {
            int cb = ts * 16 + l15 + kw;
            if (cb > 57) cb = 57;                // only lanes whose outputs are discarded
            bf16x8 bfm = *(const bf16x8*)(lb + (size_t)cb * LSTR);
#pragma unroll
            for (int tc = 0; tc < 4; ++tc)
                acc[tc][ts] = __builtin_amdgcn_mfma_f32_16x16x32_bf16(
                    cur[tc], bfm, acc[tc][ts], 0, 0, 0);
        }
        if (p < 34) {                            // prefetch p+2 into the buffer just freed
            const int pn = p + 2;
            const bf16_t* wp = wpbase + (size_t)(pn >> 2) * (COUT * CIN) + (pn & 3) * 32;
#pragma unroll
            for (int tc = 0; tc < 4; ++tc)
                cur[tc] = *(const bf16x8*)(wp + tc * 16 * CIN);
        }
    }

    // ---- epilogue: D col = lane&15 -> w, row = l4*4+i -> co  (R1-verified mapping)
    const int h   = h0 + ws;
    const int co0 = wc * 64;
    float* obase = out + ((size_t)n * COUT) * HW + (size_t)h * WW;
#pragma unroll
    for (int tc = 0; tc < 4; ++tc) {
#pragma unroll
        for (int ts = 0; ts < 4; ++ts) {
            int w0 = ts * 16 + l15;
            if (w0 < WW) {
#pragma unroll
                for (int i = 0; i < 4; ++i) {
                    int co = co0 + tc * 16 + l4 * 4 + i;
                    obase[(size_t)co * HW + w0] = acc[tc][ts][i] + bias[co];
                }
            }
        }
    }
}

extern "C" void kernel_launch(void* const* d_in, const int* in_sizes, int n_in,
                              void* d_out, int out_size, void* d_ws, size_t ws_size,
                              hipStream_t stream) {
    const float* in   = (const float*)d_in[0];
    const float* wgt  = (const float*)d_in[1];
    const float* bias = (const float*)d_in[2];
    float* out = (float*)d_out;

    bf16_t* Wt = (bf16_t*)d_ws;                  // 294,912 B

    wtrans_kernel<<<64, 256, 0, stream>>>(wgt, Wt);
    conv_fused_kernel<<<NIMG * ROWPAIRS, 256, 0, stream>>>(in, Wt, bias, out);
}

// Round 5
// 102.289 us; speedup vs baseline: 1.6345x; 1.1802x over previous
//
#include <hip/hip_runtime.h>
#include <stdint.h>
#include <stddef.h>

typedef __bf16 bf16_t;
typedef __bf16 bf16x8 __attribute__((ext_vector_type(8)));
typedef float  f32x4  __attribute__((ext_vector_type(4)));

#define NIMG 16
#define CIN  128
#define COUT 128
#define HH   56
#define WW   56
#define HW   (HH * WW)       // 3136
#define CDIM 58              // staged c extent: c = w+1, w = -1..56
#define LSTR 136             // LDS c-stride in bf16: 272B = 68 dwords -> bank stride 4 (2-way, free)
#define ROWPAIRS 28

// ---------- prologue: W[co][ci][3][3] fp32 -> Wt2 fragment-major bf16 ----------
// Wt2 record r = (khkw*4+chunk)*8 + wc*4 + tc  (512 bf16 = 1 KB, lane-contiguous):
//   element (lane = l4*16+l15, j) = W[co = wc*64+tc*16+l15][ci = chunk*32+l4*8+j][khkw]
// -> conv's per-fragment load is ONE contiguous 1 KB burst (16 B/lane, lane-consecutive).
__global__ void wtrans_kernel(const float* __restrict__ w, bf16_t* __restrict__ wt2) {
    int idx = blockIdx.x * 256 + threadIdx.x;    // 16384 threads: one (co,ci) each
    int co = idx >> 7, ci = idx & 127;
    const float* src = w + (size_t)idx * 9;
    float v[9];
#pragma unroll
    for (int k = 0; k < 9; ++k) v[k] = src[k];
    int chunk = ci >> 5, l4 = (ci >> 3) & 3, j = ci & 7;
    int wc = co >> 6, tc = (co >> 4) & 3, l15 = co & 15;
    int lane = l4 * 16 + l15;
#pragma unroll
    for (int k = 0; k < 9; ++k) {
        size_t rec = (size_t)((k * 4 + chunk) * 8 + wc * 4 + tc);
        wt2[rec * 512 + lane * 8 + j] = (bf16_t)v[k];
    }
}

// ---------- fused conv: block = (n, 2 output rows) x 128 co; 4 waves 64sp x 64co ----------
// Input resident in LDS (staged once, padded stride); weights register-double-buffered
// from L2 with prefetch distance 2, now as contiguous 1 KB fragment bursts.
__global__ __launch_bounds__(256, 2)
void conv_fused_kernel(const float* __restrict__ in, const bf16_t* __restrict__ Wt2,
                       const float* __restrict__ bias, float* __restrict__ out) {
    __shared__ bf16_t inp[4 * CDIM * LSTR];      // 63,104 B -> 2 blocks/CU

    const int bx = blockIdx.x;
    const int n  = bx / ROWPAIRS;
    const int h0 = (bx % ROWPAIRS) * 2;          // output rows h0, h0+1; input rows h0-1..h0+2

    const int tid  = threadIdx.x;
    const int lane = tid & 63;
    const int wave = tid >> 6;
    const int ws  = wave & 1;                    // output row within pair
    const int wc  = wave >> 1;                   // co half (64)
    const int l15 = lane & 15;
    const int l4  = lane >> 4;

    // ---- stage input once: unit G = cig*232 + rr*58 + c  (c fastest -> contiguous walk)
#pragma unroll
    for (int it = 0; it < 15; ++it) {
        int G = it * 256 + tid;
        if (G < 3712) {
            int cig = G / 232, rem = G - cig * 232;
            int rr  = rem / 58, c  = rem - rr * 58;
            int r_in = h0 - 1 + rr, w = c - 1;
            uint32_t u[8];
            if (r_in >= 0 && r_in < HH && w >= 0 && w < WW) {
                const float* src = in + (((size_t)n * CIN + cig * 8) * HH + r_in) * WW + w;
                float v[8];
#pragma unroll
                for (int j = 0; j < 8; ++j) v[j] = src[(size_t)j * HW];   // 8 independent strided loads
#pragma unroll
                for (int j = 0; j < 8; ++j) { bf16_t b = (bf16_t)v[j]; u[j] = *(const uint16_t*)&b; }
            } else {
#pragma unroll
                for (int j = 0; j < 8; ++j) u[j] = 0;
            }
            uint4 o;
            o.x = u[0] | (u[1] << 16); o.y = u[2] | (u[3] << 16);
            o.z = u[4] | (u[5] << 16); o.w = u[6] | (u[7] << 16);
            *(uint4*)&inp[(rr * CDIM + c) * LSTR + cig * 8] = o;
        }
    }
    __syncthreads();                             // the only barrier

    f32x4 acc[4][4];                             // [co tile][sp tile]
#pragma unroll
    for (int a = 0; a < 4; ++a)
#pragma unroll
        for (int b2 = 0; b2 < 4; ++b2) acc[a][b2] = (f32x4){0.f, 0.f, 0.f, 0.f};

    // fragment pointer base: record (p*8 + wc*4 + tc), this lane's 8 elements
    const bf16_t* wpbase = Wt2 + (size_t)(wc * 4) * 512 + (size_t)lane * 8;

    bf16x8 afa[4], afb[4];                       // rotating buffers, prefetch distance 2
#pragma unroll
    for (int tc = 0; tc < 4; ++tc)
        afa[tc] = *(const bf16x8*)(wpbase + (size_t)tc * 512);                   // p=0
#pragma unroll
    for (int tc = 0; tc < 4; ++tc)
        afb[tc] = *(const bf16x8*)(wpbase + (size_t)(8 + tc) * 512);             // p=1

#pragma unroll 4
    for (int p = 0; p < 36; ++p) {
        const int khkw = p >> 2, chunk = p & 3;
        const int kh = khkw / 3, kw = khkw - kh * 3;
        const int r  = ws + kh;
        const bf16_t* lb = inp + (size_t)(r * CDIM) * LSTR + chunk * 32 + l4 * 8;

        bf16x8* cur = (p & 1) ? afb : afa;
#pragma unroll
        for (int ts = 0; ts < 4; ++ts) {
            int cb = ts * 16 + l15 + kw;
            if (cb > 57) cb = 57;                // only lanes whose outputs are discarded
            bf16x8 bfm = *(const bf16x8*)(lb + (size_t)cb * LSTR);
#pragma unroll
            for (int tc = 0; tc < 4; ++tc)
                acc[tc][ts] = __builtin_amdgcn_mfma_f32_16x16x32_bf16(
                    cur[tc], bfm, acc[tc][ts], 0, 0, 0);
        }
        if (p < 34) {                            // prefetch p+2 into the buffer just freed
            const bf16_t* wp = wpbase + (size_t)(p + 2) * 8 * 512;
#pragma unroll
            for (int tc = 0; tc < 4; ++tc)
                cur[tc] = *(const bf16x8*)(wp + (size_t)tc * 512);
        }
    }

    // ---- epilogue: D col = lane&15 -> w, row = l4*4+i -> co  (R1-verified mapping)
    const int h   = h0 + ws;
    const int co0 = wc * 64;
    float* obase = out + ((size_t)n * COUT) * HW + (size_t)h * WW;
#pragma unroll
    for (int tc = 0; tc < 4; ++tc) {
#pragma unroll
        for (int ts = 0; ts < 4; ++ts) {
            int w0 = ts * 16 + l15;
            if (w0 < WW) {
#pragma unroll
                for (int i = 0; i < 4; ++i) {
                    int co = co0 + tc * 16 + l4 * 4 + i;
                    obase[(size_t)co * HW + w0] = acc[tc][ts][i] + bias[co];
                }
            }
        }
    }
}

extern "C" void kernel_launch(void* const* d_in, const int* in_sizes, int n_in,
                              void* d_out, int out_size, void* d_ws, size_t ws_size,
                              hipStream_t stream) {
    const float* in   = (const float*)d_in[0];
    const float* wgt  = (const float*)d_in[1];
    const float* bias = (const float*)d_in[2];
    float* out = (float*)d_out;

    bf16_t* Wt2 = (bf16_t*)d_ws;                 // 294,912 B, fragment-major

    wtrans_kernel<<<64, 256, 0, stream>>>(wgt, Wt2);
    conv_fused_kernel<<<NIMG * ROWPAIRS, 256, 0, stream>>>(in, Wt2, bias, out);
}

// Round 6
// 97.338 us; speedup vs baseline: 1.7176x; 1.0509x over previous
//
#include <hip/hip_runtime.h>
#include <stdint.h>
#include <stddef.h>

typedef __bf16 bf16_t;
typedef __bf16 bf16x8 __attribute__((ext_vector_type(8)));
typedef float  f32x4  __attribute__((ext_vector_type(4)));

#define NIMG 16
#define CIN  128
#define COUT 128
#define HH   56
#define WW   56
#define HW   (HH * WW)       // 3136
#define CDIM 58              // staged c extent: c = w+1, w = -1..56
#define LSTR 136             // LDS c-stride in bf16: 272B = 68 dwords -> bank stride 4 (2-way, free)
#define ROWPAIRS 28

// ---------- prologue: W[co][ci][3][3] fp32 -> Wt2 fragment-major bf16 ----------
// Wt2 record r = (khkw*4+chunk)*8 + (co>>4)  (512 bf16 = 1 KB, lane-contiguous):
//   element (lane = l4*16+l15, j) = W[co = (co>>4)*16+l15][ci = chunk*32+l4*8+j][khkw]
// -> conv's per-fragment load is ONE contiguous 1 KB burst (16 B/lane, lane-consecutive).
__global__ void wtrans_kernel(const float* __restrict__ w, bf16_t* __restrict__ wt2) {
    int idx = blockIdx.x * 256 + threadIdx.x;    // 16384 threads: one (co,ci) each
    int co = idx >> 7, ci = idx & 127;
    const float* src = w + (size_t)idx * 9;
    float v[9];
#pragma unroll
    for (int k = 0; k < 9; ++k) v[k] = src[k];
    int chunk = ci >> 5, l4 = (ci >> 3) & 3, j = ci & 7;
    int cotile = co >> 4, l15 = co & 15;
    int lane = l4 * 16 + l15;
#pragma unroll
    for (int k = 0; k < 9; ++k) {
        size_t rec = (size_t)((k * 4 + chunk) * 8 + cotile);
        wt2[rec * 512 + lane * 8 + j] = (bf16_t)v[k];
    }
}

// ---------- fused conv: block = (n, 2 rows) x 128 co; 512 thr = 8 waves 64sp x 32co ----------
// 2 blocks/CU -> 16 waves/CU (4/SIMD). Input resident in LDS; weights in NAMED register
// pairs, prefetch distance 2 phases, 1 KB contiguous bursts. One barrier total.
#define DO_PHASE(P, F0, F1) do {                                                     \
    const int khkw_ = (P) >> 2, chunk_ = (P) & 3;                                    \
    const int kh_ = khkw_ / 3, kw_ = khkw_ - kh_ * 3;                                \
    const bf16_t* lb_ = inp + (size_t)((ws + kh_) * CDIM) * LSTR + chunk_ * 32 + l4 * 8; \
    _Pragma("unroll")                                                                \
    for (int ts = 0; ts < 4; ++ts) {                                                 \
        int cb_ = ts * 16 + l15 + kw_;                                               \
        if (cb_ > 57) cb_ = 57;   /* only lanes whose outputs are discarded */       \
        bf16x8 bfm_ = *(const bf16x8*)(lb_ + (size_t)cb_ * LSTR);                    \
        acc[0][ts] = __builtin_amdgcn_mfma_f32_16x16x32_bf16(F0, bfm_, acc[0][ts], 0, 0, 0); \
        acc[1][ts] = __builtin_amdgcn_mfma_f32_16x16x32_bf16(F1, bfm_, acc[1][ts], 0, 0, 0); \
    }                                                                                \
} while (0)

#define PREFETCH(P, F0, F1) do {                                                     \
    const bf16_t* wp_ = wpbase + (size_t)(P) * 8 * 512;                              \
    F0 = *(const bf16x8*)(wp_);                                                      \
    F1 = *(const bf16x8*)(wp_ + 512);                                                \
} while (0)

__global__ __launch_bounds__(512, 4)
void conv_fused_kernel(const float* __restrict__ in, const bf16_t* __restrict__ Wt2,
                       const float* __restrict__ bias, float* __restrict__ out) {
    __shared__ bf16_t inp[4 * CDIM * LSTR];      // 63,104 B -> 2 blocks/CU

    const int bx = blockIdx.x;
    const int n  = bx / ROWPAIRS;
    const int h0 = (bx % ROWPAIRS) * 2;          // output rows h0, h0+1; input rows h0-1..h0+2

    const int tid  = threadIdx.x;
    const int lane = tid & 63;
    const int wave = tid >> 6;                   // 0..7
    const int ws  = wave & 1;                    // output row within pair
    const int wc  = wave >> 1;                   // co quarter (32 co)
    const int l15 = lane & 15;
    const int l4  = lane >> 4;

    // ---- stage input once: unit G = cig*232 + rr*58 + c  (c fastest -> contiguous walk)
#pragma unroll
    for (int it = 0; it < 8; ++it) {
        int G = it * 512 + tid;
        if (G < 3712) {
            int cig = G / 232, rem = G - cig * 232;
            int rr  = rem / 58, c  = rem - rr * 58;
            int r_in = h0 - 1 + rr, w = c - 1;
            uint32_t u[8];
            if (r_in >= 0 && r_in < HH && w >= 0 && w < WW) {
                const float* src = in + (((size_t)n * CIN + cig * 8) * HH + r_in) * WW + w;
                float v[8];
#pragma unroll
                for (int j = 0; j < 8; ++j) v[j] = src[(size_t)j * HW];   // 8 independent strided loads
#pragma unroll
                for (int j = 0; j < 8; ++j) { bf16_t b = (bf16_t)v[j]; u[j] = *(const uint16_t*)&b; }
            } else {
#pragma unroll
                for (int j = 0; j < 8; ++j) u[j] = 0;
            }
            uint4 o;
            o.x = u[0] | (u[1] << 16); o.y = u[2] | (u[3] << 16);
            o.z = u[4] | (u[5] << 16); o.w = u[6] | (u[7] << 16);
            *(uint4*)&inp[(rr * CDIM + c) * LSTR + cig * 8] = o;
        }
    }
    __syncthreads();                             // the only barrier

    f32x4 acc[2][4];                             // [co tile][sp tile]
#pragma unroll
    for (int a = 0; a < 2; ++a)
#pragma unroll
        for (int b2 = 0; b2 < 4; ++b2) acc[a][b2] = (f32x4){0.f, 0.f, 0.f, 0.f};

    // fragment base: record (p*8 + wc*2 + tc), this lane's 8 bf16
    const bf16_t* wpbase = Wt2 + (size_t)(wc * 2) * 512 + (size_t)lane * 8;

    bf16x8 A0, A1, B0, B1;                       // named regs: no arrays, no spill risk
    PREFETCH(0, A0, A1);
    PREFETCH(1, B0, B1);

#pragma unroll
    for (int pp = 0; pp < 17; ++pp) {
        const int p0 = pp * 2;
        DO_PHASE(p0, A0, A1);
        PREFETCH(p0 + 2, A0, A1);
        DO_PHASE(p0 + 1, B0, B1);
        PREFETCH(p0 + 3, B0, B1);
    }
    DO_PHASE(34, A0, A1);
    DO_PHASE(35, B0, B1);

    // ---- epilogue: D col = lane&15 -> w, row = l4*4+i -> co  (verified mapping)
    const int h   = h0 + ws;
    const int co0 = wc * 32;
    float* obase = out + ((size_t)n * COUT) * HW + (size_t)h * WW;
#pragma unroll
    for (int tc = 0; tc < 2; ++tc) {
#pragma unroll
        for (int ts = 0; ts < 4; ++ts) {
            int w0 = ts * 16 + l15;
            if (w0 < WW) {
#pragma unroll
                for (int i = 0; i < 4; ++i) {
                    int co = co0 + tc * 16 + l4 * 4 + i;
                    obase[(size_t)co * HW + w0] = acc[tc][ts][i] + bias[co];
                }
            }
        }
    }
}

extern "C" void kernel_launch(void* const* d_in, const int* in_sizes, int n_in,
                              void* d_out, int out_size, void* d_ws, size_t ws_size,
                              hipStream_t stream) {
    const float* in   = (const float*)d_in[0];
    const float* wgt  = (const float*)d_in[1];
    const float* bias = (const float*)d_in[2];
    float* out = (float*)d_out;

    bf16_t* Wt2 = (bf16_t*)d_ws;                 // 294,912 B, fragment-major

    wtrans_kernel<<<64, 256, 0, stream>>>(wgt, Wt2);
    conv_fused_kernel<<<NIMG * ROWPAIRS, 512, 0, stream>>>(in, Wt2, bias, out);
}

// Round 7
// 96.383 us; speedup vs baseline: 1.7347x; 1.0099x over previous
//
#include <hip/hip_runtime.h>
#include <stdint.h>
#include <stddef.h>

typedef __bf16 bf16_t;
typedef __bf16 bf16x8 __attribute__((ext_vector_type(8)));
typedef float  f32x4  __attribute__((ext_vector_type(4)));

#define NIMG 16
#define CIN  128
#define COUT 128
#define HH   56
#define WW   56
#define HW   (HH * WW)       // 3136
#define CDIM 58              // staged c extent: c = w+1, w = -1..56
#define LSTR 136             // LDS c-stride in bf16: 272B = 68 dwords -> bank stride 4
#define ROWPAIRS 28

// ---------- prologue: W[co][ci][3][3] fp32 -> Wt2 fragment-major bf16 ----------
// record rec = (khkw*4+chunk)*8 + (co>>4); element (lane=l4*16+l15, j) =
//   W[co=(co>>4)*16+l15][ci=chunk*32+l4*8+j][khkw]   (1 KB lane-contiguous bursts)
__global__ void wtrans_kernel(const float* __restrict__ w, bf16_t* __restrict__ wt2) {
    int idx = blockIdx.x * 256 + threadIdx.x;    // 16384 threads: one (co,ci) each
    int co = idx >> 7, ci = idx & 127;
    const float* src = w + (size_t)idx * 9;
    float v[9];
#pragma unroll
    for (int k = 0; k < 9; ++k) v[k] = src[k];
    int chunk = ci >> 5, l4 = (ci >> 3) & 3, j = ci & 7;
    int cotile = co >> 4, l15 = co & 15;
    int lane = l4 * 16 + l15;
#pragma unroll
    for (int k = 0; k < 9; ++k) {
        size_t rec = (size_t)((k * 4 + chunk) * 8 + cotile);
        wt2[rec * 512 + lane * 8 + j] = (bf16_t)v[k];
    }
}

// ---------- fused conv: block = (n, 2 rows) x 128 co; 512 thr = 8 waves ----------
// wave = ks*4 + wc*2 + ws: tile 64sp x 64co (tc=4, ts=4), K split in half by ks
// (chunks {2ks,2ks+1} x 9 khkw = 18 phases). LDS cross-wave reduce at the end.
// i = khkw*2 + cs, cs = i&1; weight record offset for phase i (ks folded into base):
#define FRAG_OFF(I) ((size_t)((((I) >> 1) * 4 + ((I) & 1)) * 8) * 512)

#define DO_PHASE(I, F0, F1, F2, F3) do {                                             \
    const int kh_ = ((I) >> 1) / 3, kw_ = ((I) >> 1) % 3;                            \
    const bf16_t* lb_ = lbbase + (size_t)((ws + kh_) * CDIM) * LSTR + ((I) & 1) * 32;\
    _Pragma("unroll")                                                                \
    for (int ts = 0; ts < 4; ++ts) {                                                 \
        int cb_ = ts * 16 + l15 + kw_;                                               \
        if (cb_ > 57) cb_ = 57;   /* only lanes whose outputs are discarded */       \
        bf16x8 bfm_ = *(const bf16x8*)(lb_ + (size_t)cb_ * LSTR);                    \
        acc[0][ts] = __builtin_amdgcn_mfma_f32_16x16x32_bf16(F0, bfm_, acc[0][ts], 0, 0, 0); \
        acc[1][ts] = __builtin_amdgcn_mfma_f32_16x16x32_bf16(F1, bfm_, acc[1][ts], 0, 0, 0); \
        acc[2][ts] = __builtin_amdgcn_mfma_f32_16x16x32_bf16(F2, bfm_, acc[2][ts], 0, 0, 0); \
        acc[3][ts] = __builtin_amdgcn_mfma_f32_16x16x32_bf16(F3, bfm_, acc[3][ts], 0, 0, 0); \
    }                                                                                \
} while (0)

#define PREFETCH(I, F0, F1, F2, F3) do {                                             \
    const bf16_t* wp_ = wpbase + FRAG_OFF(I);                                        \
    F0 = *(const bf16x8*)(wp_);                                                      \
    F1 = *(const bf16x8*)(wp_ + 512);                                                \
    F2 = *(const bf16x8*)(wp_ + 1024);                                               \
    F3 = *(const bf16x8*)(wp_ + 1536);                                               \
} while (0)

__global__ __launch_bounds__(512, 4)
void conv_fused_kernel(const float* __restrict__ in, const bf16_t* __restrict__ Wt2,
                       const float* __restrict__ bias, float* __restrict__ out) {
    __shared__ __align__(16) unsigned char smem[65536];   // input stage 63104 B / reduce 65536 B
    bf16_t* inp = (bf16_t*)smem;

    const int bx = blockIdx.x;
    const int n  = bx / ROWPAIRS;
    const int h0 = (bx % ROWPAIRS) * 2;          // output rows h0,h0+1; input rows h0-1..h0+2

    const int tid  = threadIdx.x;
    const int lane = tid & 63;
    const int wave = tid >> 6;                   // 0..7
    const int ws  = wave & 1;                    // output row within pair
    const int wc  = (wave >> 1) & 1;             // co half (64)
    const int ks  = wave >> 2;                   // K half (chunks 2ks, 2ks+1)
    const int l15 = lane & 15;
    const int l4  = lane >> 4;

    // ---- stage input once: unit G = cig*232 + rr*58 + c (c fastest -> contiguous walk)
#pragma unroll
    for (int it = 0; it < 8; ++it) {
        int G = it * 512 + tid;
        if (G < 3712) {
            int cig = G / 232, rem = G - cig * 232;
            int rr  = rem / 58, c  = rem - rr * 58;
            int r_in = h0 - 1 + rr, w = c - 1;
            uint32_t u[8];
            if (r_in >= 0 && r_in < HH && w >= 0 && w < WW) {
                const float* src = in + (((size_t)n * CIN + cig * 8) * HH + r_in) * WW + w;
                float v[8];
#pragma unroll
                for (int j = 0; j < 8; ++j) v[j] = src[(size_t)j * HW];   // 8 independent loads
#pragma unroll
                for (int j = 0; j < 8; ++j) { bf16_t b = (bf16_t)v[j]; u[j] = *(const uint16_t*)&b; }
            } else {
#pragma unroll
                for (int j = 0; j < 8; ++j) u[j] = 0;
            }
            uint4 o;
            o.x = u[0] | (u[1] << 16); o.y = u[2] | (u[3] << 16);
            o.z = u[4] | (u[5] << 16); o.w = u[6] | (u[7] << 16);
            *(uint4*)&inp[(rr * CDIM + c) * LSTR + cig * 8] = o;
        }
    }
    __syncthreads();

    f32x4 acc[4][4];                             // [co tile][sp tile]
#pragma unroll
    for (int a = 0; a < 4; ++a)
#pragma unroll
        for (int b2 = 0; b2 < 4; ++b2) acc[a][b2] = (f32x4){0.f, 0.f, 0.f, 0.f};

    // weight fragment base: rec = (khkw*4 + ks*2 + cs)*8 + wc*4 + tc
    const bf16_t* wpbase = Wt2 + (size_t)(ks * 16 + wc * 4) * 512 + (size_t)lane * 8;
    // LDS B base: this wave's ci offset = ks*64 + l4*8 (within a 32-chunk, +cs*32 in DO_PHASE)
    const bf16_t* lbbase = inp + ks * 64 + l4 * 8;

    bf16x8 A0, A1, A2, A3, B0, B1, B2, B3;       // named regs, prefetch distance 2
    PREFETCH(0, A0, A1, A2, A3);
    PREFETCH(1, B0, B1, B2, B3);

#pragma unroll
    for (int ii = 0; ii < 8; ++ii) {
        const int i0 = ii * 2;
        DO_PHASE(i0, A0, A1, A2, A3);
        PREFETCH(i0 + 2, A0, A1, A2, A3);
        DO_PHASE(i0 + 1, B0, B1, B2, B3);
        PREFETCH(i0 + 3, B0, B1, B2, B3);
    }
    DO_PHASE(16, A0, A1, A2, A3);
    DO_PHASE(17, B0, B1, B2, B3);

    // ---- cross-wave K reduction through LDS (pair (ws,wc,ks=1) -> (ws,wc,ks=0))
    __syncthreads();                             // K-loop LDS reads done; safe to overwrite
    float* red = (float*)smem;
    const int q = wc * 2 + ws;                   // 0..3
    if (ks == 1) {
#pragma unroll
        for (int tc = 0; tc < 4; ++tc)
#pragma unroll
            for (int ts = 0; ts < 4; ++ts)
                *(f32x4*)(red + (size_t)q * 4096 + (tc * 4 + ts) * 256 + lane * 4) = acc[tc][ts];
    }
    __syncthreads();
    if (ks == 0) {
        const int h   = h0 + ws;
        const int co0 = wc * 64;
        float* obase = out + ((size_t)n * COUT) * HW + (size_t)h * WW;
#pragma unroll
        for (int tc = 0; tc < 4; ++tc) {
#pragma unroll
            for (int ts = 0; ts < 4; ++ts) {
                f32x4 oth = *(const f32x4*)(red + (size_t)q * 4096 + (tc * 4 + ts) * 256 + lane * 4);
                f32x4 r = acc[tc][ts] + oth;
                int w0 = ts * 16 + l15;
                if (w0 < WW) {
#pragma unroll
                    for (int i = 0; i < 4; ++i) {
                        int co = co0 + tc * 16 + l4 * 4 + i;
                        obase[(size_t)co * HW + w0] = r[i] + bias[co];
                    }
                }
            }
        }
    }
}

extern "C" void kernel_launch(void* const* d_in, const int* in_sizes, int n_in,
                              void* d_out, int out_size, void* d_ws, size_t ws_size,
                              hipStream_t stream) {
    const float* in   = (const float*)d_in[0];
    const float* wgt  = (const float*)d_in[1];
    const float* bias = (const float*)d_in[2];
    float* out = (float*)d_out;

    bf16_t* Wt2 = (bf16_t*)d_ws;                 // 294,912 B, fragment-major

    wtrans_kernel<<<64, 256, 0, stream>>>(wgt, Wt2);
    conv_fused_kernel<<<NIMG * ROWPAIRS, 512, 0, stream>>>(in, Wt2, bias, out);
}